// Round 4
// baseline (1061.916 us; speedup 1.0000x reference)
//
#include <hip/hip_runtime.h>
#include <hip/hip_bf16.h>

typedef __bf16 bf16_t;
typedef __bf16 bf16x8 __attribute__((ext_vector_type(8)));
typedef float  f32x4  __attribute__((ext_vector_type(4)));

#define CIN  64
#define COUT 128
#define HH   224
#define WW   224
#define OH   222
#define OW   222
#define XT_RS 72   // padded ci-stride (144 B rows: A-frag b128 reads land balanced on banks)

// -------- prepack: wpk[off][co][ci] = bf16(w[co][ci][kh][kw]), off = kh*3+kw
__global__ void prepack_w(const float* __restrict__ w, bf16_t* __restrict__ wpk) {
    int idx = blockIdx.x * 256 + threadIdx.x;
    if (idx >= 9 * COUT * CIN) return;
    int ci  = idx & 63;
    int co  = (idx >> 6) & 127;
    int off = idx >> 13;               // 128*64 = 8192 = 2^13
    wpk[idx] = (bf16_t)w[(co * CIN + ci) * 9 + off];
}

// -------- main: implicit-GEMM conv + bias + channel-min + tanh(tanh)
// B-operand (weights) read directly from L2-resident wpk each tap: no wl LDS
// staging, no per-tap barriers -> compiler pipelines the whole 9-tap loop.
__global__ __launch_bounds__(256, 4) void conv_min_tanh(
    const float* __restrict__ x, const float* __restrict__ w,
    const float* __restrict__ bias, const bf16_t* __restrict__ wpk,
    float* __restrict__ out)
{
    __shared__ __align__(16) bf16_t xt[10 * 18 * XT_RS];  // 25,920 B
    __shared__ float red[2][8][16];                        // 1 KB  (total 26.9 KB)

    const int tid = threadIdx.x;
    const int lane = tid & 63;
    const int wv  = tid >> 6;
    const int wgM = wv >> 1;        // pixel-row group: rows 0-3 / 4-7
    const int wgN = wv & 1;         // co group: 0-63 / 64-127
    const int l15 = lane & 15;
    const int lg  = lane >> 4;      // k-group / D-row group

    const int owb = blockIdx.x * 16;
    const int ohb = blockIdx.y * 8;
    const int b   = blockIdx.z;

    // ---- stage x tile (fp32 -> bf16), rows ohb..ohb+9, cols owb..owb+17, 64 ci
    // float2-vectorized: 5760 float2 elements, c2 = pair-of-columns index.
    const float* xb = x + (size_t)b * (CIN * HH * WW);
    for (int idx = tid; idx < 9 * 10 * CIN; idx += 256) {
        int c2 = idx % 9;
        int r  = (idx / 9) % 10;
        int ci = idx / 90;
        int rg = ohb + r; if (rg > HH - 1) rg = HH - 1;   // clamp feeds only
        int cg = owb + 2 * c2;                             // discarded outputs
        float2 v;
        if (cg + 1 <= WW - 1) {
            v = *reinterpret_cast<const float2*>(&xb[(ci * HH + rg) * WW + cg]);
        } else {
            float a = xb[(ci * HH + rg) * WW + (WW - 1)];
            v = make_float2(a, a);
        }
        bf16_t* dst = &xt[(r * 18 + 2 * c2) * XT_RS + ci];
        dst[0]     = (bf16_t)v.x;
        dst[XT_RS] = (bf16_t)v.y;
    }

    // ---- per-lane bias for the 4 N-frags
    float bias4[4];
#pragma unroll
    for (int ni = 0; ni < 4; ni++) bias4[ni] = bias[wgN * 64 + ni * 16 + l15];

    f32x4 acc[4][4];
#pragma unroll
    for (int mi = 0; mi < 4; mi++)
#pragma unroll
        for (int ni = 0; ni < 4; ni++)
            acc[mi][ni] = (f32x4){0.f, 0.f, 0.f, 0.f};

    __syncthreads();   // xt ready — the ONLY pre-epilogue barrier

    // ---- K loop: 9 taps x 2 K-steps of 32 ci, barrier-free
#pragma unroll
    for (int off = 0; off < 9; off++) {
        const int kh = off / 3, kw = off % 3;

        // B-frags straight from global (wpk is L2-resident: 147 KB total)
        bf16x8 bfr[2][4];
#pragma unroll
        for (int kk = 0; kk < 2; kk++)
#pragma unroll
            for (int ni = 0; ni < 4; ni++) {
                int co = wgN * 64 + ni * 16 + l15;
                if (wpk) {
                    bfr[kk][ni] = *reinterpret_cast<const bf16x8*>(
                        wpk + (size_t)(off * COUT + co) * CIN + kk * 32 + lg * 8);
                } else {   // fallback: gather fp32 weights, convert
                    bf16x8 t;
#pragma unroll
                    for (int j = 0; j < 8; j++)
                        t[j] = (bf16_t)w[(co * CIN + kk * 32 + lg * 8 + j) * 9 + off];
                    bfr[kk][ni] = t;
                }
            }

#pragma unroll
        for (int kk = 0; kk < 2; kk++) {
            bf16x8 af[4];
#pragma unroll
            for (int mi = 0; mi < 4; mi++) {
                int row = wgM * 4 + mi + kh;       // input row in tile
                int col = l15 + kw;                // input col in tile (m-index = l15)
                af[mi] = *reinterpret_cast<const bf16x8*>(
                    &xt[(row * 18 + col) * XT_RS + kk * 32 + lg * 8]);
            }
#pragma unroll
            for (int mi = 0; mi < 4; mi++)
#pragma unroll
                for (int ni = 0; ni < 4; ni++)
                    acc[mi][ni] = __builtin_amdgcn_mfma_f32_16x16x32_bf16(
                        af[mi], bfr[kk][ni], acc[mi][ni], 0, 0, 0);
        }
    }

    // ---- epilogue: +bias, min over ni, min over co-lanes, min across wgN, tanh^2
#pragma unroll
    for (int mi = 0; mi < 4; mi++) {
#pragma unroll
        for (int r = 0; r < 4; r++) {
            float v =        acc[mi][0][r] + bias4[0];
            v = fminf(v,     acc[mi][1][r] + bias4[1]);
            v = fminf(v,     acc[mi][2][r] + bias4[2]);
            v = fminf(v,     acc[mi][3][r] + bias4[3]);
            // reduce over the 16 co held by l15 (D col dim)
            v = fminf(v, __shfl_xor(v, 1));
            v = fminf(v, __shfl_xor(v, 2));
            v = fminf(v, __shfl_xor(v, 4));
            v = fminf(v, __shfl_xor(v, 8));
            if (l15 == 0) red[wgN][wgM * 4 + mi][lg * 4 + r] = v;
        }
    }
    __syncthreads();
    if (tid < 128) {
        int prow = tid >> 4, pcol = tid & 15;
        float v = fminf(red[0][prow][pcol], red[1][prow][pcol]);
        v = tanhf(tanhf(v));
        int oh = ohb + prow, ow = owb + pcol;
        if (oh < OH && ow < OW)
            out[((size_t)b * OH + oh) * OW + ow] = v;
    }
}

extern "C" void kernel_launch(void* const* d_in, const int* in_sizes, int n_in,
                              void* d_out, int out_size, void* d_ws, size_t ws_size,
                              hipStream_t stream) {
    const float* x    = (const float*)d_in[0];
    const float* w    = (const float*)d_in[1];
    const float* bias = (const float*)d_in[2];
    float* out = (float*)d_out;

    bf16_t* wpk = nullptr;
    if (ws_size >= (size_t)(9 * COUT * CIN * 2)) {
        wpk = (bf16_t*)d_ws;
        prepack_w<<<288, 256, 0, stream>>>(w, wpk);
    }
    dim3 grid(14, 28, 16);   // 14 ow-tiles x 28 oh-tiles x 16 batch
    conv_min_tanh<<<grid, 256, 0, stream>>>(x, w, bias, wpk, out);
}

// Round 5
// 510.653 us; speedup vs baseline: 2.0795x; 2.0795x over previous
//
#include <hip/hip_runtime.h>
#include <hip/hip_bf16.h>

typedef __bf16 bf16_t;
typedef __bf16 bf16x8 __attribute__((ext_vector_type(8)));
typedef float  f32x4  __attribute__((ext_vector_type(4)));

#define CIN  64
#define COUT 128
#define HH   224
#define WW   224
#define OH   222
#define OW   222
#define XT_RS 72   // padded ci-stride (144 B rows -> balanced banks on b128 frags)

// -------- prepack: wpk[off][co][ci] = bf16(w[co][ci][kh][kw]), off = kh*3+kw
__global__ void prepack_w(const float* __restrict__ w, bf16_t* __restrict__ wpk) {
    int idx = blockIdx.x * 256 + threadIdx.x;
    if (idx >= 9 * COUT * CIN) return;
    int ci  = idx & 63;
    int co  = (idx >> 6) & 127;
    int off = idx >> 13;               // 128*64 = 8192 = 2^13
    wpk[idx] = (bf16_t)w[(co * CIN + ci) * 9 + off];
}

// -------- main: implicit-GEMM conv + bias + channel-min + tanh(tanh)
// Round-3 structure + register prefetch of next tap's weights (T14 split):
// global L2 latency hides under the current tap's ds_read+MFMA phase.
__global__ __launch_bounds__(256) void conv_min_tanh(
    const float* __restrict__ x, const float* __restrict__ w,
    const float* __restrict__ bias, const bf16_t* __restrict__ wpk,
    float* __restrict__ out)
{
    __shared__ __align__(16) bf16_t xt[10 * 18 * XT_RS];  // 25,920 B
    __shared__ __align__(16) bf16_t wl[COUT * XT_RS];     // 18,432 B
    __shared__ float red[2][8][16];                        // 1 KB (total 45.4 KB)

    const int tid = threadIdx.x;
    const int lane = tid & 63;
    const int wv  = tid >> 6;
    const int wgM = wv >> 1;        // pixel-row group: rows 0-3 / 4-7
    const int wgN = wv & 1;         // co group: 0-63 / 64-127
    const int l15 = lane & 15;
    const int lg  = lane >> 4;      // k-group / D-row group

    const int owb = blockIdx.x * 16;
    const int ohb = blockIdx.y * 8;
    const int b   = blockIdx.z;

    // weight-stage identity for this thread: co = tid>>1, half = tid&1 (32 ci = 64 B)
    const int wco = tid >> 1, whalf = tid & 1;

    // ---- prefetch tap 0 weights into registers (issued before xt staging)
    union WReg { uint4 u[4]; bf16_t h[32]; };
    WReg wreg;
    if (wpk) {
        const uint4* src = reinterpret_cast<const uint4*>(
            wpk + (size_t)(0 * COUT + wco) * CIN + whalf * 32);
#pragma unroll
        for (int j = 0; j < 4; j++) wreg.u[j] = src[j];
    } else {
#pragma unroll
        for (int j = 0; j < 32; j++)
            wreg.h[j] = (bf16_t)w[(wco * CIN + whalf * 32 + j) * 9 + 0];
    }

    // ---- stage x tile (fp32 -> bf16), rows ohb..ohb+9, cols owb..owb+17, 64 ci
    const float* xb = x + (size_t)b * (CIN * HH * WW);
    for (int idx = tid; idx < 10 * 18 * CIN; idx += 256) {
        int c  = idx % 18;
        int r  = (idx / 18) % 10;
        int ci = idx / 180;
        int rg = ohb + r; if (rg > HH - 1) rg = HH - 1;   // clamp feeds only
        int cg = owb + c; if (cg > WW - 1) cg = WW - 1;   // discarded outputs
        xt[(r * 18 + c) * XT_RS + ci] = (bf16_t)xb[(ci * HH + rg) * WW + cg];
    }

    // ---- per-lane bias for the 4 N-frags
    float bias4[4];
#pragma unroll
    for (int ni = 0; ni < 4; ni++) bias4[ni] = bias[wgN * 64 + ni * 16 + l15];

    f32x4 acc[4][4];
#pragma unroll
    for (int mi = 0; mi < 4; mi++)
#pragma unroll
        for (int ni = 0; ni < 4; ni++)
            acc[mi][ni] = (f32x4){0.f, 0.f, 0.f, 0.f};

    __syncthreads();   // xt ready; wl writable (tap loop barrier #1 for off=0)

    // ---- K loop: 9 taps; per tap: write wreg->wl, prefetch next tap, barrier,
    //      compute. unroll 1 pins prefetch depth to exactly one tap (+16 VGPR).
#pragma unroll 1
    for (int off = 0; off < 9; off++) {
        // drain prefetched weights into LDS (compiler inserts the vmcnt wait
        // here -- it has had a full tap of compute to resolve)
        {
            uint4* dst = reinterpret_cast<uint4*>(&wl[wco * XT_RS + whalf * 32]);
#pragma unroll
            for (int j = 0; j < 4; j++) dst[j] = wreg.u[j];
        }
        // issue next tap's loads now; consumed at next iteration's drain
        if (off < 8) {
            if (wpk) {
                const uint4* src = reinterpret_cast<const uint4*>(
                    wpk + (size_t)((off + 1) * COUT + wco) * CIN + whalf * 32);
#pragma unroll
                for (int j = 0; j < 4; j++) wreg.u[j] = src[j];
            } else {
#pragma unroll
                for (int j = 0; j < 32; j++)
                    wreg.h[j] = (bf16_t)w[(wco * CIN + whalf * 32 + j) * 9 + off + 1];
            }
        }
        __syncthreads();   // wl[off] visible to all waves

        const int kh = off / 3, kw = off % 3;
#pragma unroll
        for (int kk = 0; kk < 2; kk++) {
            bf16x8 af[4], bfr[4];
#pragma unroll
            for (int mi = 0; mi < 4; mi++) {
                int row = wgM * 4 + mi + kh;       // input row in tile
                int col = l15 + kw;                // input col in tile (m = l15)
                af[mi] = *reinterpret_cast<const bf16x8*>(
                    &xt[(row * 18 + col) * XT_RS + kk * 32 + lg * 8]);
            }
#pragma unroll
            for (int ni = 0; ni < 4; ni++) {
                int co = wgN * 64 + ni * 16 + l15;
                bfr[ni] = *reinterpret_cast<const bf16x8*>(
                    &wl[co * XT_RS + kk * 32 + lg * 8]);
            }
#pragma unroll
            for (int mi = 0; mi < 4; mi++)
#pragma unroll
                for (int ni = 0; ni < 4; ni++)
                    acc[mi][ni] = __builtin_amdgcn_mfma_f32_16x16x32_bf16(
                        af[mi], bfr[ni], acc[mi][ni], 0, 0, 0);
        }

        if (off < 8) __syncthreads();   // compute-readers done before next write
    }

    // ---- epilogue: +bias, min over ni, min over co-lanes, min across wgN, tanh^2
#pragma unroll
    for (int mi = 0; mi < 4; mi++) {
#pragma unroll
        for (int r = 0; r < 4; r++) {
            float v =        acc[mi][0][r] + bias4[0];
            v = fminf(v,     acc[mi][1][r] + bias4[1]);
            v = fminf(v,     acc[mi][2][r] + bias4[2]);
            v = fminf(v,     acc[mi][3][r] + bias4[3]);
            // reduce over the 16 co held by l15 (D col dim)
            v = fminf(v, __shfl_xor(v, 1));
            v = fminf(v, __shfl_xor(v, 2));
            v = fminf(v, __shfl_xor(v, 4));
            v = fminf(v, __shfl_xor(v, 8));
            if (l15 == 0) red[wgN][wgM * 4 + mi][lg * 4 + r] = v;
        }
    }
    __syncthreads();
    if (tid < 128) {
        int prow = tid >> 4, pcol = tid & 15;
        float v = fminf(red[0][prow][pcol], red[1][prow][pcol]);
        v = tanhf(tanhf(v));
        int oh = ohb + prow, ow = owb + pcol;
        if (oh < OH && ow < OW)
            out[((size_t)b * OH + oh) * OW + ow] = v;
    }
}

extern "C" void kernel_launch(void* const* d_in, const int* in_sizes, int n_in,
                              void* d_out, int out_size, void* d_ws, size_t ws_size,
                              hipStream_t stream) {
    const float* x    = (const float*)d_in[0];
    const float* w    = (const float*)d_in[1];
    const float* bias = (const float*)d_in[2];
    float* out = (float*)d_out;

    bf16_t* wpk = nullptr;
    if (ws_size >= (size_t)(9 * COUT * CIN * 2)) {
        wpk = (bf16_t*)d_ws;
        prepack_w<<<288, 256, 0, stream>>>(w, wpk);
    }
    dim3 grid(14, 28, 16);   // 14 ow-tiles x 28 oh-tiles x 16 batch
    conv_min_tanh<<<grid, 256, 0, stream>>>(x, w, bias, wpk, out);
}